// Round 6
// baseline (105.257 us; speedup 1.0000x reference)
//
#include <hip/hip_runtime.h>
#include <math.h>

#define NROWS 4096
#define NCLS  32000
#define VEC_PER_ROW (NCLS / 4)   // 8000 float4s per row
#define BLK 512
#define NV  16                   // float4 per thread: 512*16 = 8192 >= 8000
#define TAIL (VEC_PER_ROW - (NV - 1) * BLK)   // 320
#define EPSF 1e-6f
#define LN2  0.69314718055994530942f
#define L2E  1.44269504088896340736f

// ln(4095/4096), precomputed in double precision
#define LNBETA (-2.4417042724800387e-4f)
// (1 - beta) = 1/4096 exactly
#define WNUM 2.44140625e-4f

typedef float f32x4 __attribute__((ext_vector_type(4)));

__device__ __forceinline__ float max4(f32x4 v) {
    return fmaxf(fmaxf(v[0], v[1]), fmaxf(v[2], v[3]));
}
__device__ __forceinline__ float sum4(f32x4 v) {
    return (v[0] + v[1]) + (v[2] + v[3]);
}

// Fused focal + class-count + weighted atomic accumulate.
// R4 lesson: target scan must not run in the load phase (VGPR peak -> spills);
// it sits after pass B. R5 lesson: NO nontemporal loads — nt bypasses L2 and
// costs ~10% read BW on gfx950.
__global__ __launch_bounds__(BLK, 4) void focal_kernel(const float* __restrict__ pred,
                                                       const int* __restrict__ target,
                                                       float* __restrict__ out)
{
    const int row = blockIdx.x;
    const int tid = threadIdx.x;
    const f32x4* rp = reinterpret_cast<const f32x4*>(pred) + (size_t)row * VEC_PER_ROW;

    // ---- load row (plain cached loads) ----
    f32x4 x[NV];
#pragma unroll
    for (int i = 0; i < NV - 1; ++i) x[i] = rp[tid + i * BLK];
    const bool lv = tid < TAIL;
    if (lv) x[NV - 1] = rp[tid + (NV - 1) * BLK];
    else    { x[NV - 1][0] = -1e30f; x[NV - 1][1] = -1e30f; x[NV - 1][2] = -1e30f; x[NV - 1][3] = -1e30f; }

    // ---- pass A: per-thread max + sum ----
    float m = -1e30f, s1 = 0.0f;
#pragma unroll
    for (int i = 0; i < NV - 1; ++i) { m = fmaxf(m, max4(x[i])); s1 += sum4(x[i]); }
    m = fmaxf(m, max4(x[NV - 1]));
    if (lv) s1 += sum4(x[NV - 1]);

    // ---- block reduce (max, sum): 8 waves ----
    __shared__ float sm[8], ss[8];
#pragma unroll
    for (int off = 32; off > 0; off >>= 1) {
        m  = fmaxf(m, __shfl_xor(m, off));
        s1 += __shfl_xor(s1, off);
    }
    const int wid  = tid >> 6;
    const int lane = tid & 63;
    if (lane == 0) { sm[wid] = m; ss[wid] = s1; }
    __syncthreads();
    if (tid < 64) {
        float mm = (tid < 8) ? sm[tid] : -1e30f;
        float s  = (tid < 8) ? ss[tid] : 0.0f;
#pragma unroll
        for (int off = 4; off > 0; off >>= 1) {
            mm = fmaxf(mm, __shfl_xor(mm, off));
            s += __shfl_xor(s, off);
        }
        if (tid == 0) { sm[0] = mm; ss[0] = s; }
    }
    __syncthreads();
    const float M  = sm[0];
    const float S1 = ss[0];

    // ---- pass B (registers only): Z, A=Σe^t·t, Z2=Σe^2t, A2=Σe^2t·t ----
    float Z = 0.f, A = 0.f, Z2 = 0.f, A2 = 0.f;
#pragma unroll
    for (int i = 0; i < NV; ++i) {
#pragma unroll
        for (int j = 0; j < 4; ++j) {
            float t = x[i][j] - M;                        // masked lanes: t ~ -1e30 (finite)
            float e = exp2f(t * L2E);                     // e^t ; masked -> 0
            Z += e;
            A = fmaf(e, t, A);                            // fma(0, -1e30, A) = A, safe
            float e2 = e * e;
            Z2 += e2;
            A2 = fmaf(e2, t, A2);
        }
    }

    // ---- class-count scan AFTER pass B: x[] dead, registers free ----
    // n = #{b : target[b] == target[row]}; 16 KB, L2-resident after first touch.
    const int t_row = target[row];
    const int4* tg = reinterpret_cast<const int4*>(target);
    int4 ta = tg[tid];
    int4 tb = tg[tid + BLK];
    int cnt = (ta.x == t_row) + (ta.y == t_row) + (ta.z == t_row) + (ta.w == t_row)
            + (tb.x == t_row) + (tb.y == t_row) + (tb.z == t_row) + (tb.w == t_row);

    // ---- block reduce 4 accumulators + count ----
    __shared__ float r0[8], r1[8], r2[8], r3[8];
    __shared__ int   sc[8];
#pragma unroll
    for (int off = 32; off > 0; off >>= 1) {
        Z   += __shfl_xor(Z,  off);
        A   += __shfl_xor(A,  off);
        Z2  += __shfl_xor(Z2, off);
        A2  += __shfl_xor(A2, off);
        cnt += __shfl_xor(cnt, off);
    }
    if (lane == 0) { r0[wid] = Z; r1[wid] = A; r2[wid] = Z2; r3[wid] = A2; sc[wid] = cnt; }
    __syncthreads();
    if (tid < 64) {
        float a = (tid < 8) ? r0[tid] : 0.f;
        float b = (tid < 8) ? r1[tid] : 0.f;
        float c = (tid < 8) ? r2[tid] : 0.f;
        float d = (tid < 8) ? r3[tid] : 0.f;
        int  cc = (tid < 8) ? sc[tid] : 0;
#pragma unroll
        for (int off = 4; off > 0; off >>= 1) {
            a += __shfl_xor(a, off);
            b += __shfl_xor(b, off);
            c += __shfl_xor(c, off);
            d += __shfl_xor(d, off);
            cc += __shfl_xor(cc, off);
        }
        if (tid == 0) {
            float lnZ  = log2f(a) * LN2;
            float invZ = 1.0f / a;
            float T = S1 - (float)NCLS * M;
            // focal = Σ(1-p)^2 * logp, expanded in (t, lnZ)
            float focal = (T - (float)NCLS * lnZ)
                        - 2.0f * (b * invZ - lnZ)
                        + (d - lnZ * c) * (invZ * invZ);

            // class-balanced weight from scanned count n >= 1
            float u = (float)cc * LNBETA;      // n * ln(beta), small negative
            float denom;
            if (u > -0.25f) {
                // 1 - beta^n = -expm1(u) ~= -(u + u^2/2 + u^3/6 + u^4/24)
                denom = -(u * (1.f + u * (0.5f + u * (0.16666667f + u * 0.041666667f))));
            } else {
                denom = 1.f - __expf(u);
            }
            float w = WNUM / (denom + EPSF);
            // pre-scaled by -1/B: accumulated magnitude ~5e9, rounding ~1e4 << 1e8 thr
            atomicAdd(out, w * (float)t_row * focal * (-1.0f / (float)NROWS));
        }
    }
}

extern "C" void kernel_launch(void* const* d_in, const int* in_sizes, int n_in,
                              void* d_out, int out_size, void* d_ws, size_t ws_size,
                              hipStream_t stream)
{
    const float* pred  = (const float*)d_in[0];
    const int* target  = (const int*)d_in[1];
    float* out         = (float*)d_out;

    hipMemsetAsync(out, 0, sizeof(float), stream);
    focal_kernel<<<NROWS, BLK, 0, stream>>>(pred, target, out);
}

// Round 7
// 101.646 us; speedup vs baseline: 1.0355x; 1.0355x over previous
//
#include <hip/hip_runtime.h>
#include <math.h>

#define NROWS 4096
#define NCLS  32000
#define VEC_PER_ROW (NCLS / 4)   // 8000 float4s per row
#define BLK 512
#define NV  16                   // float4 per thread: 512*16 = 8192 >= 8000
#define TAIL (VEC_PER_ROW - (NV - 1) * BLK)   // 320
#define EPSF 1e-6f
#define LN2  0.69314718055994530942f
#define L2E  1.44269504088896340736f

// ln(4095/4096), precomputed in double precision
#define LNBETA (-2.4417042724800387e-4f)
// (1 - beta) = 1/4096 exactly
#define WNUM 2.44140625e-4f

#define ROWS_PER_FBLK 16         // finalize: 16 waves/block, one row per wave

__device__ __forceinline__ float max4(float4 v) {
    return fmaxf(fmaxf(v.x, v.y), fmaxf(v.z, v.w));
}
__device__ __forceinline__ float sum4(float4 v) {
    return (v.x + v.y) + (v.z + v.w);
}

// R2's focal kernel, verbatim (best measured: ~91 us, 5.8 TB/s), plus a
// single out-zeroing store from block 0 (stream-ordered before finalize).
// Lesson R4-R6: do NOT fuse anything else in here — the compiler hoists
// fused loads into the load phase and blows the 128-VGPR cap.
__global__ __launch_bounds__(BLK, 4) void focal_kernel(const float* __restrict__ pred,
                                                       float* __restrict__ focal_out,
                                                       float* __restrict__ out)
{
    const int row = blockIdx.x;
    const int tid = threadIdx.x;
    if (row == 0 && tid == 0) out[0] = 0.0f;   // zero accumulator for finalize
    const float4* rp = reinterpret_cast<const float4*>(pred) + (size_t)row * VEC_PER_ROW;

    float4 x[NV];
#pragma unroll
    for (int i = 0; i < NV - 1; ++i) x[i] = rp[tid + i * BLK];
    const bool lv = tid < TAIL;
    if (lv) x[NV - 1] = rp[tid + (NV - 1) * BLK];
    else    x[NV - 1] = make_float4(-1e30f, -1e30f, -1e30f, -1e30f);

    // ---- pass A: per-thread max + sum ----
    float m = -1e30f, s1 = 0.0f;
#pragma unroll
    for (int i = 0; i < NV - 1; ++i) { m = fmaxf(m, max4(x[i])); s1 += sum4(x[i]); }
    m = fmaxf(m, max4(x[NV - 1]));
    if (lv) s1 += sum4(x[NV - 1]);

    // ---- block reduce (max, sum): 8 waves ----
    __shared__ float sm[8], ss[8];
#pragma unroll
    for (int off = 32; off > 0; off >>= 1) {
        m  = fmaxf(m, __shfl_xor(m, off));
        s1 += __shfl_xor(s1, off);
    }
    const int wid  = tid >> 6;
    const int lane = tid & 63;
    if (lane == 0) { sm[wid] = m; ss[wid] = s1; }
    __syncthreads();
    if (tid < 64) {
        float mm = (tid < 8) ? sm[tid] : -1e30f;
        float s  = (tid < 8) ? ss[tid] : 0.0f;
#pragma unroll
        for (int off = 4; off > 0; off >>= 1) {
            mm = fmaxf(mm, __shfl_xor(mm, off));
            s += __shfl_xor(s, off);
        }
        if (tid == 0) { sm[0] = mm; ss[0] = s; }
    }
    __syncthreads();
    const float M  = sm[0];
    const float S1 = ss[0];

    // ---- pass B (registers only): Z, A=Σe^t·t, Z2=Σe^2t, A2=Σe^2t·t ----
    float Z = 0.f, A = 0.f, Z2 = 0.f, A2 = 0.f;
#pragma unroll
    for (int i = 0; i < NV; ++i) {
        float vals[4] = {x[i].x, x[i].y, x[i].z, x[i].w};
#pragma unroll
        for (int j = 0; j < 4; ++j) {
            float t = vals[j] - M;                        // masked lanes: t ~ -1e30 (finite)
            float e = exp2f(t * L2E);                     // e^t ; masked -> 0
            Z += e;
            A = fmaf(e, t, A);                            // fma(0, -1e30, A) = A, safe
            float e2 = e * e;
            Z2 += e2;
            A2 = fmaf(e2, t, A2);
        }
    }

    // ---- block reduce 4 accumulators ----
    __shared__ float r0[8], r1[8], r2[8], r3[8];
#pragma unroll
    for (int off = 32; off > 0; off >>= 1) {
        Z  += __shfl_xor(Z,  off);
        A  += __shfl_xor(A,  off);
        Z2 += __shfl_xor(Z2, off);
        A2 += __shfl_xor(A2, off);
    }
    if (lane == 0) { r0[wid] = Z; r1[wid] = A; r2[wid] = Z2; r3[wid] = A2; }
    __syncthreads();
    if (tid < 64) {
        float a = (tid < 8) ? r0[tid] : 0.f;
        float b = (tid < 8) ? r1[tid] : 0.f;
        float c = (tid < 8) ? r2[tid] : 0.f;
        float d = (tid < 8) ? r3[tid] : 0.f;
#pragma unroll
        for (int off = 4; off > 0; off >>= 1) {
            a += __shfl_xor(a, off);
            b += __shfl_xor(b, off);
            c += __shfl_xor(c, off);
            d += __shfl_xor(d, off);
        }
        if (tid == 0) {
            float lnZ  = log2f(a) * LN2;
            float invZ = 1.0f / a;
            float T = S1 - (float)NCLS * M;
            // focal = Σ(1-p)^2 * logp, expanded in (t, lnZ)
            float focal = (T - (float)NCLS * lnZ)
                        - 2.0f * (b * invZ - lnZ)
                        + (d - lnZ * c) * (invZ * invZ);
            focal_out[row] = focal;
        }
    }
}

// Parallel finalize: 256 blocks x 16 waves; wave w of block g owns row
// g*16+w. Each lane scans 16 coalesced int4 of target (L1/L2-resident),
// wave-reduces the count, lane 0 computes the weighted contribution,
// 16 waves LDS-combine, one atomicAdd per block (256 total).
__global__ __launch_bounds__(1024) void finalize_kernel(const int* __restrict__ target,
                                                        const float* __restrict__ focal,
                                                        float* __restrict__ out)
{
    const int tid  = threadIdx.x;
    const int wid  = tid >> 6;
    const int lane = tid & 63;
    const int row  = blockIdx.x * ROWS_PER_FBLK + wid;

    const int t_row = target[row];
    const int4* tg = reinterpret_cast<const int4*>(target);
    int cnt = 0;
#pragma unroll
    for (int k = 0; k < NROWS / 4 / 64; ++k) {       // 16 int4 per lane
        int4 v = tg[lane + k * 64];
        cnt += (v.x == t_row) + (v.y == t_row) + (v.z == t_row) + (v.w == t_row);
    }
#pragma unroll
    for (int off = 32; off > 0; off >>= 1) cnt += __shfl_xor(cnt, off);

    __shared__ float part[ROWS_PER_FBLK];
    if (lane == 0) {
        float u = (float)cnt * LNBETA;       // n * ln(beta), small negative
        float denom;
        if (u > -0.25f) {
            // 1 - beta^n = -expm1(u) ~= -(u + u^2/2 + u^3/6 + u^4/24)
            denom = -(u * (1.f + u * (0.5f + u * (0.16666667f + u * 0.041666667f))));
        } else {
            denom = 1.f - __expf(u);
        }
        float w = WNUM / (denom + EPSF);
        part[wid] = w * (float)t_row * focal[row] * (-1.0f / (float)NROWS);
    }
    __syncthreads();
    if (tid == 0) {
        float s = 0.f;
#pragma unroll
        for (int i = 0; i < ROWS_PER_FBLK; ++i) s += part[i];
        atomicAdd(out, s);
    }
}

extern "C" void kernel_launch(void* const* d_in, const int* in_sizes, int n_in,
                              void* d_out, int out_size, void* d_ws, size_t ws_size,
                              hipStream_t stream)
{
    const float* pred  = (const float*)d_in[0];
    const int* target  = (const int*)d_in[1];
    float* out         = (float*)d_out;

    float* focal = (float*)d_ws;   // 4096 floats

    focal_kernel<<<NROWS, BLK, 0, stream>>>(pred, focal, out);
    finalize_kernel<<<NROWS / ROWS_PER_FBLK, 1024, 0, stream>>>(target, focal, out);
}